// Round 11
// baseline (130.384 us; speedup 1.0000x reference)
//
#include <hip/hip_runtime.h>

// Problem constants (fixed by reference setup_inputs)
#define N_PRE 8192
#define N_CUR 16384
#define KNN   8

// Workspace layout (bytes):
//   [0,    64K) : c2p   u32[N_CUR]        nearest-pre index per cur point
//   [64K, 192K) : pre4  float4[N_PRE]     (-2px, -2py, -2pz, |p|^2)
//   [192K,448K) : cur4  float4[N_CUR]     ( cx,   cy,   cz,  |c|^2)
//   [448K,704K) : lists u32[N_PRE*8]      per-pre top-8 cur indices
//
// Comparator trick: for a fixed query q, ordering by true sqdist equals
// ordering by (|cand|^2 - 2 cand.q)  -> 3 FMA per candidate.
// d can be NEGATIVE -> monotone float->u32 key map for all key compares.
//
// R11 (ledger closed by R10: OH=46us fixed, prep=2, fused=68.3, fin=3;
// fusion saved ~17us vs serial but VALUBusy 69% leaves ~21us idle.
// Suspect: 16 shared __syncthreads couple 8 A-waves to 8 B-waves whose
// pop-event timing jitters -> each barrier charges the max):
//  * HETEROGENEOUS BLOCKS, not heterogeneous waves: 1024 blocks x 512thr,
//    blockIdx&1 = type. Even = B-block (R4's proven main loop verbatim:
//    8 waves x P=2, LDS cur tile, DPP ballot-pop). Odd = A-block (R10's
//    proven A: 8 waves x Q=4 branchless min, LDS pre tile).
//  * 4 blocks/CU (4 x 32KB LDS = 128 <= 160; 32 waves/CU; VGPR<=64 via
//    launch_bounds(512,8)) -> ALL 1024 blocks co-resident; parity
//    interleave => every CU hosts a type mix. A/B never share a barrier.
//  * A-blocks retire early -> B gets the whole machine for the back half.
//  * No cross-block deps, no spin (R9 lesson). finalize kernel unchanged.

#define MAPPED_INF 0xFF800000u  // monotone key of +inf (empty-slot sentinel)

#define TILE 2048   // float4 staged per iteration (32 KB), both block types

__device__ __forceinline__ unsigned key_of_bits(unsigned b) {
    return b ^ (0x80000000u | (unsigned)((int)b >> 31));
}
__device__ __forceinline__ float float_of_key(unsigned k) {
    unsigned b = k ^ (0x80000000u | ~(unsigned)((int)k >> 31));
    return __uint_as_float(b);
}

// ---------- prep: pack comparator-form coords ----------
__global__ __launch_bounds__(256) void prep_kernel(
        const float* __restrict__ pre, const float* __restrict__ cur,
        float4* __restrict__ pre4, float4* __restrict__ cur4) {
    int i = blockIdx.x * 256 + threadIdx.x;
    if (i < N_CUR) {
        float x = cur[i], y = cur[N_CUR + i], z = cur[2 * N_CUR + i];
        cur4[i] = make_float4(x, y, z, fmaf(x, x, fmaf(y, y, z * z)));
    }
    if (i < N_PRE) {
        float x = pre[i], y = pre[N_PRE + i], z = pre[2 * N_PRE + i];
        pre4[i] = make_float4(-2.f * x, -2.f * y, -2.f * z,
                              fmaf(x, x, fmaf(y, y, z * z)));
    }
}

// ---------- B-side pop: top-8 on lanes 0..7, DPP shift-up insert -------
__device__ __forceinline__ void pop_top8(float d, float& t8, unsigned& ld,
                                         unsigned& li, int jbase) {
    unsigned long long m = __ballot(d < t8);
    while (m) {
        int src = __ffsll(m) - 1;
        unsigned fdb = (unsigned)__builtin_amdgcn_readlane(__float_as_int(d), src);
        unsigned kd = key_of_bits(fdb);            // uniform (SALU)
        unsigned kj = (unsigned)(jbase + src);     // uniform (SALU)
        // shift-up within 16-lane row; lane 0 receives old=0 (kd<0u never
        // true -> slot 0 never takes the shifted value)
        unsigned ud = (unsigned)__builtin_amdgcn_update_dpp(
            0, (int)ld, 0x111, 0xF, 0xF, false);
        unsigned uj = (unsigned)__builtin_amdgcn_update_dpp(
            0, (int)li, 0x111, 0xF, 0xF, false);
        bool hi = kd < ud;   // belongs below slot-1 -> take shifted value
        bool lo = kd < ld;   // belongs here -> take new
        ld = hi ? ud : (lo ? kd : ld);
        li = hi ? uj : (lo ? kj : li);
        unsigned k7 = (unsigned)__builtin_amdgcn_readlane((int)ld, 7);
        t8 = float_of_key(k7);
        m = (m & (m - 1)) & __ballot(d < t8);
    }
}

// ---------- fused kernel: heterogeneous blocks (even=B, odd=A) ---------
__global__ __launch_bounds__(512, 8) void fused_het(
        const float4* __restrict__ pre4, const float4* __restrict__ cur4,
        unsigned* __restrict__ c2p, unsigned* __restrict__ lists) {
    __shared__ float4 sbuf[TILE];

    const int tid  = threadIdx.x;
    const int lane = tid & 63;
    const int w    = tid >> 6;              // 0..7
    const int bid  = blockIdx.x >> 1;       // 0..511 within type

    if ((blockIdx.x & 1) == 0) {
        // ================= B-block: per-pre top-8 (R4 main loop) =======
        const int ia = bid * 16 + w * 2;    // this wave's 2 pres
        const int ib = ia + 1;

        const float4 p0 = pre4[ia];         // (-2p, |p|^2), wave-uniform
        const float4 p1 = pre4[ib];

        const float INF = __int_as_float(0x7F800000);
        unsigned ld0 = MAPPED_INF, li0 = 0, ld1 = MAPPED_INF, li1 = 0;
        float t80 = INF, t81 = INF;

        for (int tile = 0; tile < N_CUR; tile += TILE) {
            __syncthreads();
            for (int k = tid; k < TILE; k += 512) sbuf[k] = cur4[tile + k];
            __syncthreads();

#pragma unroll 4
            for (int s = 0; s < TILE; s += 64) {
                float4 c = sbuf[s + lane];
                float d0 = fmaf(p0.x, c.x, fmaf(p0.y, c.y, fmaf(p0.z, c.z, c.w)));
                float d1 = fmaf(p1.x, c.x, fmaf(p1.y, c.y, fmaf(p1.z, c.z, c.w)));
                const int jbase = tile + s;
                pop_top8(d0, t80, ld0, li0, jbase);
                pop_top8(d1, t81, ld1, li1, jbase);
            }
        }

        // dump top-8 index lists (lanes 0..7, ascending)
        if (lane < 8) {
            lists[ia * 8 + lane] = li0;
            lists[ib * 8 + lane] = li1;
        }
    } else {
        // ================= A-block: cur2pre argmin (R10's A half) ======
        const int j0 = bid * 32 + w * 4;    // this wave's 4 curs

        const float4 c0 = cur4[j0 + 0];
        const float4 c1 = cur4[j0 + 1];
        const float4 c2 = cur4[j0 + 2];
        const float4 c3 = cur4[j0 + 3];

        const float INF = __int_as_float(0x7F800000);
        float b0 = INF, b1 = INF, b2 = INF, b3 = INF;
        int   i0 = 0,  i1 = 0,  i2 = 0,  i3 = 0;

        for (int tile = 0; tile < N_PRE; tile += TILE) {
            __syncthreads();
            for (int k = tid; k < TILE; k += 512) sbuf[k] = pre4[tile + k];
            __syncthreads();

#pragma unroll 4
            for (int s = 0; s < TILE; s += 64) {
                float4 q = sbuf[s + lane];
                int idx = tile + s + lane;
                float d; bool c;
                d = fmaf(q.x, c0.x, fmaf(q.y, c0.y, fmaf(q.z, c0.z, q.w)));
                c = d < b0; b0 = c ? d : b0; i0 = c ? idx : i0;
                d = fmaf(q.x, c1.x, fmaf(q.y, c1.y, fmaf(q.z, c1.z, q.w)));
                c = d < b1; b1 = c ? d : b1; i1 = c ? idx : i1;
                d = fmaf(q.x, c2.x, fmaf(q.y, c2.y, fmaf(q.z, c2.z, q.w)));
                c = d < b2; b2 = c ? d : b2; i2 = c ? idx : i2;
                d = fmaf(q.x, c3.x, fmaf(q.y, c3.y, fmaf(q.z, c3.z, q.w)));
                c = d < b3; b3 = c ? d : b3; i3 = c ? idx : i3;
            }
        }

        // packed (key,idx) butterfly min: lowest key, then lowest idx
        unsigned long long v0 =
            (((unsigned long long)key_of_bits(__float_as_uint(b0))) << 32) | (unsigned)i0;
        unsigned long long v1 =
            (((unsigned long long)key_of_bits(__float_as_uint(b1))) << 32) | (unsigned)i1;
        unsigned long long v2 =
            (((unsigned long long)key_of_bits(__float_as_uint(b2))) << 32) | (unsigned)i2;
        unsigned long long v3 =
            (((unsigned long long)key_of_bits(__float_as_uint(b3))) << 32) | (unsigned)i3;
#pragma unroll
        for (int off = 32; off > 0; off >>= 1) {
            unsigned long long o;
            o = __shfl_xor(v0, off); v0 = (o < v0) ? o : v0;
            o = __shfl_xor(v1, off); v1 = (o < v1) ? o : v1;
            o = __shfl_xor(v2, off); v2 = (o < v2) ? o : v2;
            o = __shfl_xor(v3, off); v3 = (o < v3) ? o : v3;
        }
        unsigned r = (unsigned)v0;
        r = (lane == 1) ? (unsigned)v1 : r;
        r = (lane == 2) ? (unsigned)v2 : r;
        r = (lane == 3) ? (unsigned)v3 : r;
        if (lane < 4) c2p[j0 + lane] = r;
    }
}

// ---------- finalize: masked mean from lists + c2p (tiny, ~3us) --------
__global__ __launch_bounds__(256) void finalize_kernel(
        const float4* __restrict__ pre4, const float4* __restrict__ cur4,
        const float* __restrict__ ups,
        const unsigned* __restrict__ c2p, const unsigned* __restrict__ lists,
        float* __restrict__ out) {
    const int t    = blockIdx.x * 256 + threadIdx.x;  // 0 .. 65535
    const int pg   = t >> 3;
    const int slot = t & 7;

    unsigned j = lists[t];
    float4 cc = cur4[j];
    float4 pp = pre4[pg];
    // True distance recomputed in direct form; p recovered exactly (*-0.5).
    float px = -0.5f * pp.x, py = -0.5f * pp.y, pz = -0.5f * pp.z;
    float dx = cc.x - px, dy = cc.y - py, dz = cc.z - pz;
    float dsq = fmaf(dx, dx, fmaf(dy, dy, dz * dz));
    float acc = (c2p[j] == (unsigned)pg) ? sqrtf(dsq) : 0.f;

    // 8-lane group reduce (groups are 8-aligned within the wave)
    acc += __shfl_xor(acc, 1);
    acc += __shfl_xor(acc, 2);
    acc += __shfl_xor(acc, 4);
    if (slot == 0) out[pg] = acc / ups[pg];
}

// ---------- launch ----------
extern "C" void kernel_launch(void* const* d_in, const int* in_sizes, int n_in,
                              void* d_out, int out_size, void* d_ws, size_t ws_size,
                              hipStream_t stream) {
    const float* pre = (const float*)d_in[0];   // (1,3,8192)
    const float* cur = (const float*)d_in[1];   // (1,3,16384)
    const float* ups = (const float*)d_in[2];   // (1,8192)
    float* out = (float*)d_out;                 // (1,8192)

    char* ws = (char*)d_ws;
    unsigned* c2p   = (unsigned*)ws;                          //  64 KB
    float4*   pre4  = (float4*)(ws + 65536);                  // 128 KB
    float4*   cur4  = (float4*)(ws + 65536 + 131072);         // 256 KB
    unsigned* lists = (unsigned*)(ws + 65536 + 131072 + 262144); // 256 KB

    prep_kernel<<<N_CUR / 256, 256, 0, stream>>>(pre, cur, pre4, cur4);

    // 1024 blocks x 512 thr: even blocks = B (512 of them, R4 geometry),
    // odd blocks = A (512, R10-A geometry). 4 blocks/CU, all co-resident.
    fused_het<<<1024, 512, 0, stream>>>(pre4, cur4, c2p, lists);

    // 8192 pres x 8 slots = 65536 threads
    finalize_kernel<<<N_PRE * 8 / 256, 256, 0, stream>>>(
        pre4, cur4, ups, c2p, lists, out);
}

// Round 12
// 126.490 us; speedup vs baseline: 1.0308x; 1.0308x over previous
//
#include <hip/hip_runtime.h>

// Problem constants (fixed by reference setup_inputs)
#define N_PRE 8192
#define N_CUR 16384
#define KNN   8

// Workspace layout (bytes):
//   [0,    64K) : c2p   u32[N_CUR]     nearest-pre index per cur point
//   [64K, 320K) : lists u32[N_PRE*8]   per-pre top-8 cur indices
//
// Comparator trick: for a fixed query q, ordering by true sqdist equals
// ordering by (|cand|^2 - 2 cand.q)  -> 3 FMA per candidate.
// d can be NEGATIVE -> monotone float->u32 key map for all key compares.
//
// R12 (R11 post-mortem: block-level A/B split let A-blocks retire at
// ~26us -> B ran the tail at 16 waves/CU = R4's starved config; R10's
// barrier coupling is the FEATURE — it holds A-waves resident all run
// long. R10 residual: 69% VALUBusy with 2 phase-locked 1024-thr blocks
// whose 16 workgroup-wide barriers drain half the CU in sync):
//  * Same R10 wave-level fusion, FINER blocks: 1024 blocks x 512 thr
//    (4 B-waves + 4 A-waves), 4 blocks/CU, NITER=16, 24KB LDS/block.
//    Each barrier gates 8 waves (25% of CU); 4 independent blocks
//    decorrelate -> drains fillable by other blocks' waves.
//  * prep FOLDED into staging: raw pre/cur packed into comparator form
//    on the fly (identical arithmetic -> identical bits); queries packed
//    inline; finalize reads raw arrays (-0.5*(-2x)=x exact). One fewer
//    launch; pre4/cur4 workspace gone.
//  * A path (branchless min, Q=4) and B path (P=2, DPP ballot-pop)
//    verbatim from R10. Scan order unchanged -> tie-breaks exact.

#define MAPPED_INF 0xFF800000u  // monotone key of +inf (empty-slot sentinel)

#define NITER  16
#define BTILE  1024   // cur staged per iteration (16 KB)
#define ATILE  512    // pre staged per iteration (8 KB)

__device__ __forceinline__ unsigned key_of_bits(unsigned b) {
    return b ^ (0x80000000u | (unsigned)((int)b >> 31));
}
__device__ __forceinline__ float float_of_key(unsigned k) {
    unsigned b = k ^ (0x80000000u | ~(unsigned)((int)k >> 31));
    return __uint_as_float(b);
}

// ---------- B-side pop: top-8 on lanes 0..7, DPP shift-up insert -------
__device__ __forceinline__ void pop_top8(float d, float& t8, unsigned& ld,
                                         unsigned& li, int jbase) {
    unsigned long long m = __ballot(d < t8);
    while (m) {
        int src = __ffsll(m) - 1;
        unsigned fdb = (unsigned)__builtin_amdgcn_readlane(__float_as_int(d), src);
        unsigned kd = key_of_bits(fdb);            // uniform (SALU)
        unsigned kj = (unsigned)(jbase + src);     // uniform (SALU)
        // shift-up within 16-lane row; lane 0 receives old=0 (kd<0u never
        // true -> slot 0 never takes the shifted value)
        unsigned ud = (unsigned)__builtin_amdgcn_update_dpp(
            0, (int)ld, 0x111, 0xF, 0xF, false);
        unsigned uj = (unsigned)__builtin_amdgcn_update_dpp(
            0, (int)li, 0x111, 0xF, 0xF, false);
        bool hi = kd < ud;   // belongs below slot-1 -> take shifted value
        bool lo = kd < ld;   // belongs here -> take new
        ld = hi ? ud : (lo ? kd : ld);
        li = hi ? uj : (lo ? kj : li);
        unsigned k7 = (unsigned)__builtin_amdgcn_readlane((int)ld, 7);
        t8 = float_of_key(k7);
        m = (m & (m - 1)) & __ballot(d < t8);
    }
}

// ---------- on-the-fly packing (bit-identical to old prep kernel) ------
__device__ __forceinline__ float4 pack_pre_q(const float* __restrict__ pre,
                                             int i) {
    float x = pre[i], y = pre[N_PRE + i], z = pre[2 * N_PRE + i];
    return make_float4(-2.f * x, -2.f * y, -2.f * z,
                       fmaf(x, x, fmaf(y, y, z * z)));
}
__device__ __forceinline__ float4 pack_cur_q(const float* __restrict__ cur,
                                             int j) {
    float x = cur[j], y = cur[N_CUR + j], z = cur[2 * N_CUR + j];
    return make_float4(x, y, z, fmaf(x, x, fmaf(y, y, z * z)));
}

// ---------- fused kernel: 4 B-waves + 4 A-waves per 512-thr block ------
__global__ __launch_bounds__(512, 8) void fused_ab(
        const float* __restrict__ pre, const float* __restrict__ cur,
        unsigned* __restrict__ c2p, unsigned* __restrict__ lists) {
    __shared__ float4 sB[BTILE];   // cur tile (B-waves consume)
    __shared__ float4 sA[ATILE];   // pre tile (A-waves consume)

    const int tid  = threadIdx.x;
    const int lane = tid & 63;
    const int w    = tid >> 6;          // 0..7
    const bool isB = (w < 4);

    // B-waves: 2 pres each (8/block). A-waves: 4 curs each (16/block).
    const int ia = blockIdx.x * 8 + w * 2;            // B: pres [ia, ia+1]
    const int wa = w - 4;                             // A wave index 0..3
    const int j0 = blockIdx.x * 16 + wa * 4;          // A: curs [j0, j0+4)

    float4 p0, p1, c0, c1, c2, c3;
    if (isB) {
        p0 = pack_pre_q(pre, ia);
        p1 = pack_pre_q(pre, ia + 1);
    } else {
        c0 = pack_cur_q(cur, j0 + 0);
        c1 = pack_cur_q(cur, j0 + 1);
        c2 = pack_cur_q(cur, j0 + 2);
        c3 = pack_cur_q(cur, j0 + 3);
    }

    const float INF = __int_as_float(0x7F800000);
    // B state: top-8 lists (lanes 0..7 ascending) for 2 pres
    unsigned ld0 = MAPPED_INF, li0 = 0, ld1 = MAPPED_INF, li1 = 0;
    float t80 = INF, t81 = INF;
    // A state: branchless running min for 4 curs
    float b0 = INF, b1 = INF, b2 = INF, b3 = INF;
    int   i0 = 0,  i1 = 0,  i2 = 0,  i3 = 0;

    for (int it = 0; it < NITER; ++it) {
        __syncthreads();
        // cooperative staging WITH packing: 2 cur + 1 pre element/thread
        {
            int e0 = it * BTILE + tid;
            int e1 = e0 + 512;
            float x0 = cur[e0], y0 = cur[N_CUR + e0], z0 = cur[2 * N_CUR + e0];
            float x1 = cur[e1], y1 = cur[N_CUR + e1], z1 = cur[2 * N_CUR + e1];
            int e2 = it * ATILE + tid;
            float px = pre[e2], py = pre[N_PRE + e2], pz = pre[2 * N_PRE + e2];
            sB[tid]       = make_float4(x0, y0, z0,
                                        fmaf(x0, x0, fmaf(y0, y0, z0 * z0)));
            sB[tid + 512] = make_float4(x1, y1, z1,
                                        fmaf(x1, x1, fmaf(y1, y1, z1 * z1)));
            sA[tid]       = make_float4(-2.f * px, -2.f * py, -2.f * pz,
                                        fmaf(px, px, fmaf(py, py, pz * pz)));
        }
        __syncthreads();

        if (isB) {
#pragma unroll 4
            for (int s = 0; s < BTILE; s += 64) {
                float4 c = sB[s + lane];
                float d0 = fmaf(p0.x, c.x, fmaf(p0.y, c.y, fmaf(p0.z, c.z, c.w)));
                float d1 = fmaf(p1.x, c.x, fmaf(p1.y, c.y, fmaf(p1.z, c.z, c.w)));
                const int jbase = it * BTILE + s;
                pop_top8(d0, t80, ld0, li0, jbase);
                pop_top8(d1, t81, ld1, li1, jbase);
            }
        } else {
#pragma unroll 4
            for (int s = 0; s < ATILE; s += 64) {
                float4 q = sA[s + lane];
                int idx = it * ATILE + s + lane;
                float d; bool c;
                d = fmaf(q.x, c0.x, fmaf(q.y, c0.y, fmaf(q.z, c0.z, q.w)));
                c = d < b0; b0 = c ? d : b0; i0 = c ? idx : i0;
                d = fmaf(q.x, c1.x, fmaf(q.y, c1.y, fmaf(q.z, c1.z, q.w)));
                c = d < b1; b1 = c ? d : b1; i1 = c ? idx : i1;
                d = fmaf(q.x, c2.x, fmaf(q.y, c2.y, fmaf(q.z, c2.z, q.w)));
                c = d < b2; b2 = c ? d : b2; i2 = c ? idx : i2;
                d = fmaf(q.x, c3.x, fmaf(q.y, c3.y, fmaf(q.z, c3.z, q.w)));
                c = d < b3; b3 = c ? d : b3; i3 = c ? idx : i3;
            }
        }
    }
    // no barriers below this point

    if (!isB) {
        // ---- A epilogue: packed (key,idx) butterfly min, write c2p ----
        unsigned long long v0 =
            (((unsigned long long)key_of_bits(__float_as_uint(b0))) << 32) | (unsigned)i0;
        unsigned long long v1 =
            (((unsigned long long)key_of_bits(__float_as_uint(b1))) << 32) | (unsigned)i1;
        unsigned long long v2 =
            (((unsigned long long)key_of_bits(__float_as_uint(b2))) << 32) | (unsigned)i2;
        unsigned long long v3 =
            (((unsigned long long)key_of_bits(__float_as_uint(b3))) << 32) | (unsigned)i3;
#pragma unroll
        for (int off = 32; off > 0; off >>= 1) {
            unsigned long long o;
            o = __shfl_xor(v0, off); v0 = (o < v0) ? o : v0;
            o = __shfl_xor(v1, off); v1 = (o < v1) ? o : v1;
            o = __shfl_xor(v2, off); v2 = (o < v2) ? o : v2;
            o = __shfl_xor(v3, off); v3 = (o < v3) ? o : v3;
        }
        unsigned r = (unsigned)v0;
        r = (lane == 1) ? (unsigned)v1 : r;
        r = (lane == 2) ? (unsigned)v2 : r;
        r = (lane == 3) ? (unsigned)v3 : r;
        if (lane < 4) c2p[j0 + lane] = r;
    } else {
        // ---- B epilogue: dump top-8 index lists (lanes 0..7, ascending)
        if (lane < 8) {
            lists[ia * 8 + lane] = li0;
            lists[(ia + 1) * 8 + lane] = li1;
        }
    }
}

// ---------- finalize: masked mean from lists + c2p (raw coords) --------
__global__ __launch_bounds__(256) void finalize_kernel(
        const float* __restrict__ pre, const float* __restrict__ cur,
        const float* __restrict__ ups,
        const unsigned* __restrict__ c2p, const unsigned* __restrict__ lists,
        float* __restrict__ out) {
    const int t    = blockIdx.x * 256 + threadIdx.x;  // 0 .. 65535
    const int pg   = t >> 3;
    const int slot = t & 7;

    unsigned j = lists[t];
    // raw coords: identical values to the old -0.5*(-2x) recovery
    float cx = cur[j], cy = cur[N_CUR + j], cz = cur[2 * N_CUR + j];
    float px = pre[pg], py = pre[N_PRE + pg], pz = pre[2 * N_PRE + pg];
    float dx = cx - px, dy = cy - py, dz = cz - pz;
    float dsq = fmaf(dx, dx, fmaf(dy, dy, dz * dz));
    float acc = (c2p[j] == (unsigned)pg) ? sqrtf(dsq) : 0.f;

    // 8-lane group reduce (groups are 8-aligned within the wave)
    acc += __shfl_xor(acc, 1);
    acc += __shfl_xor(acc, 2);
    acc += __shfl_xor(acc, 4);
    if (slot == 0) out[pg] = acc / ups[pg];
}

// ---------- launch ----------
extern "C" void kernel_launch(void* const* d_in, const int* in_sizes, int n_in,
                              void* d_out, int out_size, void* d_ws, size_t ws_size,
                              hipStream_t stream) {
    const float* pre = (const float*)d_in[0];   // (1,3,8192)
    const float* cur = (const float*)d_in[1];   // (1,3,16384)
    const float* ups = (const float*)d_in[2];   // (1,8192)
    float* out = (float*)d_out;                 // (1,8192)

    char* ws = (char*)d_ws;
    unsigned* c2p   = (unsigned*)ws;            //  64 KB
    unsigned* lists = (unsigned*)(ws + 65536);  // 256 KB

    // 1024 blocks x 512 thr (4 B-waves + 4 A-waves each), 4 blocks/CU,
    // 24KB LDS/block; prep folded into staging. 2 launches total.
    fused_ab<<<1024, 512, 0, stream>>>(pre, cur, c2p, lists);

    // 8192 pres x 8 slots = 65536 threads
    finalize_kernel<<<N_PRE * 8 / 256, 256, 0, stream>>>(
        pre, cur, ups, c2p, lists, out);
}

// Round 13
// 121.629 us; speedup vs baseline: 1.0720x; 1.0400x over previous
//
#include <hip/hip_runtime.h>

// Problem constants (fixed by reference setup_inputs)
#define N_PRE 8192
#define N_CUR 16384
#define KNN   8

// Workspace layout (bytes):
//   [0,    64K) : c2p   u32[N_CUR]        nearest-pre index per cur point
//   [64K, 192K) : pre4  float4[N_PRE]     (-2px, -2py, -2pz, |p|^2)
//   [192K,448K) : cur4  float4[N_CUR]     ( cx,   cy,   cz,  |c|^2)
//   [448K,704K) : lists u32[N_PRE*8]      per-pre top-8 cur indices
//
// Comparator trick: for a fixed query q, ordering by true sqdist equals
// ordering by (|cand|^2 - 2 cand.q)  -> 3 FMA per candidate.
// d can be NEGATIVE -> monotone float->u32 key map for all key compares.
//
// R13 = R10 (best measured: fused=68.3us, total=119.4) + T14 async-STAGE
// split. R11 (block-level A/B split) and R12 (finer blocks + scalar
// packing staging) both regressed -> R10's geometry is the local optimum
// of the fusion family. The one unaddressed stall in R10: per iteration
// the 3 float4 staging loads (L2, ~300cy) sit BETWEEN the two barriers,
// synchronized across all 16 waves. T14: issue next tile's loads right
// after the LDS-ready barrier (latency hides under the whole compute
// phase); only the ds_write remains between barriers. +12 VGPR, same
// barrier semantics, same scan order -> bit-identical results.
//  * waves 0-7: B main (P=2, LDS cur tile, DPP ballot-pop — R4-proven).
//  * waves 8-15: A (Q=4 branchless running min — R6-proven).
//  * A writes c2p; B writes top-8 index lists; finalize kernel does the
//    masked mean (no cross-block deps, no spin — R9 lesson).

#define MAPPED_INF 0xFF800000u  // monotone key of +inf (empty-slot sentinel)

#define NITER  8
#define ATILE  1024   // pre4 staged per iteration (16 KB)
#define BTILE  2048   // cur4 staged per iteration (32 KB)

__device__ __forceinline__ unsigned key_of_bits(unsigned b) {
    return b ^ (0x80000000u | (unsigned)((int)b >> 31));
}
__device__ __forceinline__ float float_of_key(unsigned k) {
    unsigned b = k ^ (0x80000000u | ~(unsigned)((int)k >> 31));
    return __uint_as_float(b);
}

// ---------- prep: pack comparator-form coords ----------
__global__ __launch_bounds__(256) void prep_kernel(
        const float* __restrict__ pre, const float* __restrict__ cur,
        float4* __restrict__ pre4, float4* __restrict__ cur4) {
    int i = blockIdx.x * 256 + threadIdx.x;
    if (i < N_CUR) {
        float x = cur[i], y = cur[N_CUR + i], z = cur[2 * N_CUR + i];
        cur4[i] = make_float4(x, y, z, fmaf(x, x, fmaf(y, y, z * z)));
    }
    if (i < N_PRE) {
        float x = pre[i], y = pre[N_PRE + i], z = pre[2 * N_PRE + i];
        pre4[i] = make_float4(-2.f * x, -2.f * y, -2.f * z,
                              fmaf(x, x, fmaf(y, y, z * z)));
    }
}

// ---------- B-side pop: top-8 on lanes 0..7, DPP shift-up insert -------
__device__ __forceinline__ void pop_top8(float d, float& t8, unsigned& ld,
                                         unsigned& li, int jbase) {
    unsigned long long m = __ballot(d < t8);
    while (m) {
        int src = __ffsll(m) - 1;
        unsigned fdb = (unsigned)__builtin_amdgcn_readlane(__float_as_int(d), src);
        unsigned kd = key_of_bits(fdb);            // uniform (SALU)
        unsigned kj = (unsigned)(jbase + src);     // uniform (SALU)
        // shift-up within 16-lane row; lane 0 receives old=0 (kd<0u never
        // true -> slot 0 never takes the shifted value)
        unsigned ud = (unsigned)__builtin_amdgcn_update_dpp(
            0, (int)ld, 0x111, 0xF, 0xF, false);
        unsigned uj = (unsigned)__builtin_amdgcn_update_dpp(
            0, (int)li, 0x111, 0xF, 0xF, false);
        bool hi = kd < ud;   // belongs below slot-1 -> take shifted value
        bool lo = kd < ld;   // belongs here -> take new
        ld = hi ? ud : (lo ? kd : ld);
        li = hi ? uj : (lo ? kj : li);
        unsigned k7 = (unsigned)__builtin_amdgcn_readlane((int)ld, 7);
        t8 = float_of_key(k7);
        m = (m & (m - 1)) & __ballot(d < t8);
    }
}

// ---------- fused kernel: 8 B-waves + 8 A-waves, T14 staged ------------
__global__ __launch_bounds__(1024, 8) void fused_ab(
        const float4* __restrict__ pre4, const float4* __restrict__ cur4,
        unsigned* __restrict__ c2p, unsigned* __restrict__ lists) {
    __shared__ float4 sA[ATILE];   // pre tile (A-waves consume)
    __shared__ float4 sB[BTILE];   // cur tile (B-waves consume)

    const int tid  = threadIdx.x;
    const int lane = tid & 63;
    const int w    = tid >> 6;          // 0..15
    const bool isB = (w < 8);

    // B-waves: 2 pres each.  A-waves: 4 curs each.
    const int ia = blockIdx.x * 16 + w * 2;          // B: pres [ia, ia+1]
    const int wa = w - 8;                            // A wave index 0..7
    const int j0 = blockIdx.x * 32 + wa * 4;         // A: curs [j0, j0+4)

    float4 p0, p1, c0, c1, c2, c3;
    if (isB) {
        p0 = pre4[ia];
        p1 = pre4[ia + 1];
    } else {
        c0 = cur4[j0 + 0];
        c1 = cur4[j0 + 1];
        c2 = cur4[j0 + 2];
        c3 = cur4[j0 + 3];
    }

    const float INF = __int_as_float(0x7F800000);
    // B state: top-8 lists (lanes 0..7 ascending) for 2 pres
    unsigned ld0 = MAPPED_INF, li0 = 0, ld1 = MAPPED_INF, li1 = 0;
    float t80 = INF, t81 = INF;
    // A state: branchless running min for 4 curs
    float b0 = INF, b1 = INF, b2 = INF, b3 = INF;
    int   i0 = 0,  i1 = 0,  i2 = 0,  i3 = 0;

    // T14 prologue: tile 0's staging data lives in registers
    float4 rB0 = cur4[tid];
    float4 rB1 = cur4[1024 + tid];
    float4 rA0 = pre4[tid];

    for (int it = 0; it < NITER; ++it) {
        __syncthreads();               // all waves done reading old tile
        sB[tid]        = rB0;          // write-late: regs -> LDS
        sB[tid + 1024] = rB1;
        sA[tid]        = rA0;
        __syncthreads();               // tile ready

        // issue-early: next tile's loads fly under the compute phase
        if (it + 1 < NITER) {
            rB0 = cur4[(it + 1) * BTILE + tid];
            rB1 = cur4[(it + 1) * BTILE + 1024 + tid];
            rA0 = pre4[(it + 1) * ATILE + tid];
        }

        if (isB) {
#pragma unroll 4
            for (int s = 0; s < BTILE; s += 64) {
                float4 c = sB[s + lane];
                float d0 = fmaf(p0.x, c.x, fmaf(p0.y, c.y, fmaf(p0.z, c.z, c.w)));
                float d1 = fmaf(p1.x, c.x, fmaf(p1.y, c.y, fmaf(p1.z, c.z, c.w)));
                const int jbase = it * BTILE + s;
                pop_top8(d0, t80, ld0, li0, jbase);
                pop_top8(d1, t81, ld1, li1, jbase);
            }
        } else {
#pragma unroll 4
            for (int s = 0; s < ATILE; s += 64) {
                float4 q = sA[s + lane];
                int idx = it * ATILE + s + lane;
                float d; bool c;
                d = fmaf(q.x, c0.x, fmaf(q.y, c0.y, fmaf(q.z, c0.z, q.w)));
                c = d < b0; b0 = c ? d : b0; i0 = c ? idx : i0;
                d = fmaf(q.x, c1.x, fmaf(q.y, c1.y, fmaf(q.z, c1.z, q.w)));
                c = d < b1; b1 = c ? d : b1; i1 = c ? idx : i1;
                d = fmaf(q.x, c2.x, fmaf(q.y, c2.y, fmaf(q.z, c2.z, q.w)));
                c = d < b2; b2 = c ? d : b2; i2 = c ? idx : i2;
                d = fmaf(q.x, c3.x, fmaf(q.y, c3.y, fmaf(q.z, c3.z, q.w)));
                c = d < b3; b3 = c ? d : b3; i3 = c ? idx : i3;
            }
        }
    }
    // no barriers below this point

    if (!isB) {
        // ---- A epilogue: packed (key,idx) butterfly min, write c2p ----
        unsigned long long v0 =
            (((unsigned long long)key_of_bits(__float_as_uint(b0))) << 32) | (unsigned)i0;
        unsigned long long v1 =
            (((unsigned long long)key_of_bits(__float_as_uint(b1))) << 32) | (unsigned)i1;
        unsigned long long v2 =
            (((unsigned long long)key_of_bits(__float_as_uint(b2))) << 32) | (unsigned)i2;
        unsigned long long v3 =
            (((unsigned long long)key_of_bits(__float_as_uint(b3))) << 32) | (unsigned)i3;
#pragma unroll
        for (int off = 32; off > 0; off >>= 1) {
            unsigned long long o;
            o = __shfl_xor(v0, off); v0 = (o < v0) ? o : v0;
            o = __shfl_xor(v1, off); v1 = (o < v1) ? o : v1;
            o = __shfl_xor(v2, off); v2 = (o < v2) ? o : v2;
            o = __shfl_xor(v3, off); v3 = (o < v3) ? o : v3;
        }
        unsigned r = (unsigned)v0;
        r = (lane == 1) ? (unsigned)v1 : r;
        r = (lane == 2) ? (unsigned)v2 : r;
        r = (lane == 3) ? (unsigned)v3 : r;
        if (lane < 4) c2p[j0 + lane] = r;
    } else {
        // ---- B epilogue: dump top-8 index lists (lanes 0..7, ascending)
        if (lane < 8) {
            lists[ia * 8 + lane] = li0;
            lists[(ia + 1) * 8 + lane] = li1;
        }
    }
}

// ---------- finalize: masked mean from lists + c2p (tiny, ~3us) --------
__global__ __launch_bounds__(256) void finalize_kernel(
        const float4* __restrict__ pre4, const float4* __restrict__ cur4,
        const float* __restrict__ ups,
        const unsigned* __restrict__ c2p, const unsigned* __restrict__ lists,
        float* __restrict__ out) {
    const int t    = blockIdx.x * 256 + threadIdx.x;  // 0 .. 65535
    const int pg   = t >> 3;
    const int slot = t & 7;

    unsigned j = lists[t];
    float4 cc = cur4[j];
    float4 pp = pre4[pg];
    // True distance recomputed in direct form; p recovered exactly (*-0.5).
    float px = -0.5f * pp.x, py = -0.5f * pp.y, pz = -0.5f * pp.z;
    float dx = cc.x - px, dy = cc.y - py, dz = cc.z - pz;
    float dsq = fmaf(dx, dx, fmaf(dy, dy, dz * dz));
    float acc = (c2p[j] == (unsigned)pg) ? sqrtf(dsq) : 0.f;

    // 8-lane group reduce (groups are 8-aligned within the wave)
    acc += __shfl_xor(acc, 1);
    acc += __shfl_xor(acc, 2);
    acc += __shfl_xor(acc, 4);
    if (slot == 0) out[pg] = acc / ups[pg];
}

// ---------- launch ----------
extern "C" void kernel_launch(void* const* d_in, const int* in_sizes, int n_in,
                              void* d_out, int out_size, void* d_ws, size_t ws_size,
                              hipStream_t stream) {
    const float* pre = (const float*)d_in[0];   // (1,3,8192)
    const float* cur = (const float*)d_in[1];   // (1,3,16384)
    const float* ups = (const float*)d_in[2];   // (1,8192)
    float* out = (float*)d_out;                 // (1,8192)

    char* ws = (char*)d_ws;
    unsigned* c2p   = (unsigned*)ws;                          //  64 KB
    float4*   pre4  = (float4*)(ws + 65536);                  // 128 KB
    float4*   cur4  = (float4*)(ws + 65536 + 131072);         // 256 KB
    unsigned* lists = (unsigned*)(ws + 65536 + 131072 + 262144); // 256 KB

    prep_kernel<<<N_CUR / 256, 256, 0, stream>>>(pre, cur, pre4, cur4);

    // 512 blocks x 16 waves (8 B-main + 8 A); R10 geometry + T14 staging.
    fused_ab<<<512, 1024, 0, stream>>>(pre4, cur4, c2p, lists);

    // 8192 pres x 8 slots = 65536 threads
    finalize_kernel<<<N_PRE * 8 / 256, 256, 0, stream>>>(
        pre4, cur4, ups, c2p, lists, out);
}

// Round 14
// 118.232 us; speedup vs baseline: 1.1028x; 1.0287x over previous
//
#include <hip/hip_runtime.h>

// Problem constants (fixed by reference setup_inputs)
#define N_PRE 8192
#define N_CUR 16384
#define KNN   8

// Workspace layout (bytes):
//   [0,    64K) : c2p   u32[N_CUR]        nearest-pre index per cur point
//   [64K, 192K) : pre4  float4[N_PRE]     (-2px, -2py, -2pz, |p|^2)
//   [192K,448K) : cur4  float4[N_CUR]     ( cx,   cy,   cz,  |c|^2)
//   [448K,704K) : lists u32[N_PRE*8]      per-pre top-8 cur indices
//
// Comparator trick: for a fixed query q, ordering by true sqdist equals
// ordering by (|cand|^2 - 2 cand.q)  -> 3 FMA per candidate.
// d can be NEGATIVE -> monotone float->u32 key map for all key compares.
//
// R14 = R10 VERBATIM (session best: fused=68.3us, total=119.4us).
// Closure of the optimization family:
//  - R11 block-level A/B split: A-blocks retire early -> starved B tail (78.6)
//  - R12 finer blocks + inline packing: occupancy fell, staging scalarized (78.5)
//  - R13 T14 prefetch: VGPR cap 64 @ launch_bounds(1024,8) -> scratch
//    spills (WRITE_SIZE 320KB -> 8.5MB), fused 70.5
// Ledger (cross-validated R0-R13): OH~46us fixed harness cost + prep 2 +
// fused 68.3 + finalize 3 = 119.3. Residual fused idle (31% VALU) is
// structural: serial ballot->readlane->DPP event chains + barrier quantum.
//  * waves 0-7: B main (P=2, LDS cur tile, DPP ballot-pop — R4-proven).
//  * waves 8-15: A (Q=4 branchless running min — R6-proven).
//  * A writes c2p; B writes top-8 index lists; finalize does the masked
//    mean (no cross-block deps, no spin — R9 lesson).

#define MAPPED_INF 0xFF800000u  // monotone key of +inf (empty-slot sentinel)

#define NITER  8
#define ATILE  1024   // pre4 staged per iteration (16 KB)
#define BTILE  2048   // cur4 staged per iteration (32 KB)

__device__ __forceinline__ unsigned key_of_bits(unsigned b) {
    return b ^ (0x80000000u | (unsigned)((int)b >> 31));
}
__device__ __forceinline__ float float_of_key(unsigned k) {
    unsigned b = k ^ (0x80000000u | ~(unsigned)((int)k >> 31));
    return __uint_as_float(b);
}

// ---------- prep: pack comparator-form coords ----------
__global__ __launch_bounds__(256) void prep_kernel(
        const float* __restrict__ pre, const float* __restrict__ cur,
        float4* __restrict__ pre4, float4* __restrict__ cur4) {
    int i = blockIdx.x * 256 + threadIdx.x;
    if (i < N_CUR) {
        float x = cur[i], y = cur[N_CUR + i], z = cur[2 * N_CUR + i];
        cur4[i] = make_float4(x, y, z, fmaf(x, x, fmaf(y, y, z * z)));
    }
    if (i < N_PRE) {
        float x = pre[i], y = pre[N_PRE + i], z = pre[2 * N_PRE + i];
        pre4[i] = make_float4(-2.f * x, -2.f * y, -2.f * z,
                              fmaf(x, x, fmaf(y, y, z * z)));
    }
}

// ---------- B-side pop: top-8 on lanes 0..7, DPP shift-up insert -------
__device__ __forceinline__ void pop_top8(float d, float& t8, unsigned& ld,
                                         unsigned& li, int jbase) {
    unsigned long long m = __ballot(d < t8);
    while (m) {
        int src = __ffsll(m) - 1;
        unsigned fdb = (unsigned)__builtin_amdgcn_readlane(__float_as_int(d), src);
        unsigned kd = key_of_bits(fdb);            // uniform (SALU)
        unsigned kj = (unsigned)(jbase + src);     // uniform (SALU)
        // shift-up within 16-lane row; lane 0 receives old=0 (kd<0u never
        // true -> slot 0 never takes the shifted value)
        unsigned ud = (unsigned)__builtin_amdgcn_update_dpp(
            0, (int)ld, 0x111, 0xF, 0xF, false);
        unsigned uj = (unsigned)__builtin_amdgcn_update_dpp(
            0, (int)li, 0x111, 0xF, 0xF, false);
        bool hi = kd < ud;   // belongs below slot-1 -> take shifted value
        bool lo = kd < ld;   // belongs here -> take new
        ld = hi ? ud : (lo ? kd : ld);
        li = hi ? uj : (lo ? kj : li);
        unsigned k7 = (unsigned)__builtin_amdgcn_readlane((int)ld, 7);
        t8 = float_of_key(k7);
        m = (m & (m - 1)) & __ballot(d < t8);
    }
}

// ---------- fused kernel: A-waves + B-main waves, no cross-block deps --
__global__ __launch_bounds__(1024, 8) void fused_ab(
        const float4* __restrict__ pre4, const float4* __restrict__ cur4,
        unsigned* __restrict__ c2p, unsigned* __restrict__ lists) {
    __shared__ float4 sA[ATILE];   // pre tile (A-waves consume)
    __shared__ float4 sB[BTILE];   // cur tile (B-waves consume)

    const int tid  = threadIdx.x;
    const int lane = tid & 63;
    const int w    = tid >> 6;          // 0..15
    const bool isB = (w < 8);

    // B-waves: 2 pres each.  A-waves: 4 curs each.
    const int ia = blockIdx.x * 16 + w * 2;          // B: pres [ia, ia+1]
    const int wa = w - 8;                            // A wave index 0..7
    const int j0 = blockIdx.x * 32 + wa * 4;         // A: curs [j0, j0+4)

    float4 p0, p1, c0, c1, c2, c3;
    if (isB) {
        p0 = pre4[ia];
        p1 = pre4[ia + 1];
    } else {
        c0 = cur4[j0 + 0];
        c1 = cur4[j0 + 1];
        c2 = cur4[j0 + 2];
        c3 = cur4[j0 + 3];
    }

    const float INF = __int_as_float(0x7F800000);
    // B state: top-8 lists (lanes 0..7 ascending) for 2 pres
    unsigned ld0 = MAPPED_INF, li0 = 0, ld1 = MAPPED_INF, li1 = 0;
    float t80 = INF, t81 = INF;
    // A state: branchless running min for 4 curs
    float b0 = INF, b1 = INF, b2 = INF, b3 = INF;
    int   i0 = 0,  i1 = 0,  i2 = 0,  i3 = 0;

    for (int it = 0; it < NITER; ++it) {
        __syncthreads();
        // cooperative staging by all 1024 threads: 2x cur4 + 1x pre4 each
        sB[tid]        = cur4[it * BTILE + tid];
        sB[tid + 1024] = cur4[it * BTILE + 1024 + tid];
        sA[tid]        = pre4[it * ATILE + tid];
        __syncthreads();

        if (isB) {
#pragma unroll 4
            for (int s = 0; s < BTILE; s += 64) {
                float4 c = sB[s + lane];
                float d0 = fmaf(p0.x, c.x, fmaf(p0.y, c.y, fmaf(p0.z, c.z, c.w)));
                float d1 = fmaf(p1.x, c.x, fmaf(p1.y, c.y, fmaf(p1.z, c.z, c.w)));
                const int jbase = it * BTILE + s;
                pop_top8(d0, t80, ld0, li0, jbase);
                pop_top8(d1, t81, ld1, li1, jbase);
            }
        } else {
#pragma unroll 4
            for (int s = 0; s < ATILE; s += 64) {
                float4 q = sA[s + lane];
                int idx = it * ATILE + s + lane;
                float d; bool c;
                d = fmaf(q.x, c0.x, fmaf(q.y, c0.y, fmaf(q.z, c0.z, q.w)));
                c = d < b0; b0 = c ? d : b0; i0 = c ? idx : i0;
                d = fmaf(q.x, c1.x, fmaf(q.y, c1.y, fmaf(q.z, c1.z, q.w)));
                c = d < b1; b1 = c ? d : b1; i1 = c ? idx : i1;
                d = fmaf(q.x, c2.x, fmaf(q.y, c2.y, fmaf(q.z, c2.z, q.w)));
                c = d < b2; b2 = c ? d : b2; i2 = c ? idx : i2;
                d = fmaf(q.x, c3.x, fmaf(q.y, c3.y, fmaf(q.z, c3.z, q.w)));
                c = d < b3; b3 = c ? d : b3; i3 = c ? idx : i3;
            }
        }
    }
    // no barriers below this point

    if (!isB) {
        // ---- A epilogue: packed (key,idx) butterfly min, write c2p ----
        unsigned long long v0 =
            (((unsigned long long)key_of_bits(__float_as_uint(b0))) << 32) | (unsigned)i0;
        unsigned long long v1 =
            (((unsigned long long)key_of_bits(__float_as_uint(b1))) << 32) | (unsigned)i1;
        unsigned long long v2 =
            (((unsigned long long)key_of_bits(__float_as_uint(b2))) << 32) | (unsigned)i2;
        unsigned long long v3 =
            (((unsigned long long)key_of_bits(__float_as_uint(b3))) << 32) | (unsigned)i3;
#pragma unroll
        for (int off = 32; off > 0; off >>= 1) {
            unsigned long long o;
            o = __shfl_xor(v0, off); v0 = (o < v0) ? o : v0;
            o = __shfl_xor(v1, off); v1 = (o < v1) ? o : v1;
            o = __shfl_xor(v2, off); v2 = (o < v2) ? o : v2;
            o = __shfl_xor(v3, off); v3 = (o < v3) ? o : v3;
        }
        unsigned r = (unsigned)v0;
        r = (lane == 1) ? (unsigned)v1 : r;
        r = (lane == 2) ? (unsigned)v2 : r;
        r = (lane == 3) ? (unsigned)v3 : r;
        if (lane < 4) c2p[j0 + lane] = r;
    } else {
        // ---- B epilogue: dump top-8 index lists (lanes 0..7, ascending)
        if (lane < 8) {
            lists[ia * 8 + lane] = li0;
            lists[(ia + 1) * 8 + lane] = li1;
        }
    }
}

// ---------- finalize: masked mean from lists + c2p (tiny, ~3us) --------
__global__ __launch_bounds__(256) void finalize_kernel(
        const float4* __restrict__ pre4, const float4* __restrict__ cur4,
        const float* __restrict__ ups,
        const unsigned* __restrict__ c2p, const unsigned* __restrict__ lists,
        float* __restrict__ out) {
    const int t    = blockIdx.x * 256 + threadIdx.x;  // 0 .. 65535
    const int pg   = t >> 3;
    const int slot = t & 7;

    unsigned j = lists[t];
    float4 cc = cur4[j];
    float4 pp = pre4[pg];
    // True distance recomputed in direct form; p recovered exactly (*-0.5).
    float px = -0.5f * pp.x, py = -0.5f * pp.y, pz = -0.5f * pp.z;
    float dx = cc.x - px, dy = cc.y - py, dz = cc.z - pz;
    float dsq = fmaf(dx, dx, fmaf(dy, dy, dz * dz));
    float acc = (c2p[j] == (unsigned)pg) ? sqrtf(dsq) : 0.f;

    // 8-lane group reduce (groups are 8-aligned within the wave)
    acc += __shfl_xor(acc, 1);
    acc += __shfl_xor(acc, 2);
    acc += __shfl_xor(acc, 4);
    if (slot == 0) out[pg] = acc / ups[pg];
}

// ---------- launch ----------
extern "C" void kernel_launch(void* const* d_in, const int* in_sizes, int n_in,
                              void* d_out, int out_size, void* d_ws, size_t ws_size,
                              hipStream_t stream) {
    const float* pre = (const float*)d_in[0];   // (1,3,8192)
    const float* cur = (const float*)d_in[1];   // (1,3,16384)
    const float* ups = (const float*)d_in[2];   // (1,8192)
    float* out = (float*)d_out;                 // (1,8192)

    char* ws = (char*)d_ws;
    unsigned* c2p   = (unsigned*)ws;                          //  64 KB
    float4*   pre4  = (float4*)(ws + 65536);                  // 128 KB
    float4*   cur4  = (float4*)(ws + 65536 + 131072);         // 256 KB
    unsigned* lists = (unsigned*)(ws + 65536 + 131072 + 262144); // 256 KB

    prep_kernel<<<N_CUR / 256, 256, 0, stream>>>(pre, cur, pre4, cur4);

    // 512 blocks x 16 waves (8 B-main + 8 A); no cross-block dependencies.
    fused_ab<<<512, 1024, 0, stream>>>(pre4, cur4, c2p, lists);

    // 8192 pres x 8 slots = 65536 threads
    finalize_kernel<<<N_PRE * 8 / 256, 256, 0, stream>>>(
        pre4, cur4, ups, c2p, lists, out);
}